// Round 1
// baseline (339.369 us; speedup 1.0000x reference)
//
#include <hip/hip_runtime.h>

// Problem constants (match reference)
#define N_   8
#define C_   256
#define H_   128
#define W_   128
#define HW_  16384
#define NB_  20
constexpr float TEMP  = 0.5f;
constexpr float IMG_W = 800.0f;
constexpr float IMG_H = 800.0f;

__device__ __forceinline__ float waveReduceSum(float v) {
    v += __shfl_xor(v, 32, 64);
    v += __shfl_xor(v, 16, 64);
    v += __shfl_xor(v, 8, 64);
    v += __shfl_xor(v, 4, 64);
    v += __shfl_xor(v, 2, 64);
    v += __shfl_xor(v, 1, 64);
    return v;
}

// K1: one pass over preds_T. Row sums (over c) -> fea_sum[n*HW+hw];
// column sums (over hw) -> chan_sum[n*C+c] via LDS partials + atomics.
// grid: 512 blocks x 256 threads. block -> n = bid&7, p = bid>>3 (64 per n),
// each block covers hw in [p*256, p*256+256), each wave 64 rows.
__global__ __launch_bounds__(256) void k_stats(const float* __restrict__ pT,
                                               float* __restrict__ chan_sum,
                                               float* __restrict__ fea_sum) {
    const int n    = blockIdx.x & 7;
    const int p    = blockIdx.x >> 3;
    const int wave = threadIdx.x >> 6;
    const int lane = threadIdx.x & 63;
    float4 cacc = make_float4(0.f, 0.f, 0.f, 0.f);
    const int hw0 = p * 256 + wave * 64;
    for (int i = 0; i < 64; ++i) {
        const int hw = hw0 + i;
        const float4 v = *(const float4*)(pT + ((size_t)(hw * N_ + n)) * C_ + lane * 4);
        const float ax = fabsf(v.x), ay = fabsf(v.y), az = fabsf(v.z), aw = fabsf(v.w);
        cacc.x += ax; cacc.y += ay; cacc.z += az; cacc.w += aw;
        const float s = waveReduceSum(ax + ay + az + aw);
        if (lane == 0) fea_sum[n * HW_ + hw] = s;   // raw sum over c (scale later)
    }
    __shared__ float lds[4][C_];
    lds[wave][lane * 4 + 0] = cacc.x;
    lds[wave][lane * 4 + 1] = cacc.y;
    lds[wave][lane * 4 + 2] = cacc.z;
    lds[wave][lane * 4 + 3] = cacc.w;
    __syncthreads();
    const int c = threadIdx.x;
    const float v = lds[0][c] + lds[1][c] + lds[2][c] + lds[3][c];
    atomicAdd(&chan_sum[n * C_ + c], v);
}

// K2: per-n softmax stats (spatial max/denom) + channel attention B[n,c].
// grid: 8 blocks x 256 threads.
__global__ __launch_bounds__(256) void k_soft(const float* __restrict__ fea_sum,
                                              const float* __restrict__ chan_sum,
                                              float* __restrict__ stats,   // [0..7]=s_max, [8..15]=s_den
                                              float* __restrict__ B) {
    const int n = blockIdx.x;
    const int tid = threadIdx.x;
    __shared__ float red[256];
    // ---- spatial softmax over HW values; logit = fea_sum/(C*TEMP)
    float m = -1e30f;
    for (int i = tid; i < HW_; i += 256) m = fmaxf(m, fea_sum[n * HW_ + i]);
    red[tid] = m; __syncthreads();
    for (int s = 128; s > 0; s >>= 1) { if (tid < s) red[tid] = fmaxf(red[tid], red[tid + s]); __syncthreads(); }
    const float smax = red[0] * (1.0f / (C_ * TEMP));
    __syncthreads();
    float acc = 0.f;
    for (int i = tid; i < HW_; i += 256)
        acc += expf(fea_sum[n * HW_ + i] * (1.0f / (C_ * TEMP)) - smax);
    red[tid] = acc; __syncthreads();
    for (int s = 128; s > 0; s >>= 1) { if (tid < s) red[tid] += red[tid + s]; __syncthreads(); }
    const float sden = red[0];
    __syncthreads();
    // ---- channel softmax over C=256 values; logit = chan_sum/(HW*TEMP)
    const float lc = chan_sum[n * C_ + tid] * (1.0f / (HW_ * TEMP));
    red[tid] = lc; __syncthreads();
    for (int s = 128; s > 0; s >>= 1) { if (tid < s) red[tid] = fmaxf(red[tid], red[tid + s]); __syncthreads(); }
    const float cmax = red[0]; __syncthreads();
    const float e = expf(lc - cmax);
    red[tid] = e; __syncthreads();
    for (int s = 128; s > 0; s >>= 1) { if (tid < s) red[tid] += red[tid + s]; __syncthreads(); }
    const float cden = red[0];
    B[n * C_ + tid] = sqrtf((float)C_ * e / cden);   // sqrt(C_att)
    if (tid == 0) { stats[n] = smax; stats[N_ + n] = sden; }
}

// K3: foreground mask per (n,hw) + background count per n.
// grid: (HW/256, N) x 256.
__global__ __launch_bounds__(256) void k_mask(const float* __restrict__ gt,
                                              float* __restrict__ Mfg,
                                              float* __restrict__ bgcnt) {
    const int n = blockIdx.y;
    const int hw = blockIdx.x * 256 + threadIdx.x;
    const int h = hw >> 7, w = hw & 127;
    float fg = 0.f;
    for (int b = 0; b < NB_; ++b) {
        const float* bx = gt + ((size_t)n * NB_ + b) * 4;
        const float x1 = bx[0], y1 = bx[1], x2 = bx[2], y2 = bx[3];
        const int wmin = (int)floorf(x1 / IMG_W * (float)W_);
        const int wmax = (int)ceilf (x2 / IMG_W * (float)W_);
        const int hmin = (int)floorf(y1 / IMG_H * (float)H_);
        const int hmax = (int)ceilf (y2 / IMG_H * (float)H_);
        if (h >= hmin && h <= hmax && w >= wmin && w <= wmax) {
            const float area = 1.0f / (float)(hmax + 1 - hmin) / (float)(wmax + 1 - wmin);
            fg = fmaxf(fg, area);
        }
    }
    Mfg[n * HW_ + hw] = fg;
    __shared__ float red[256];
    red[threadIdx.x] = (fg <= 0.f) ? 1.f : 0.f;
    __syncthreads();
    for (int s = 128; s > 0; s >>= 1) { if (threadIdx.x < s) red[threadIdx.x] += red[threadIdx.x + s]; __syncthreads(); }
    if (threadIdx.x == 0) atomicAdd(&bgcnt[n], red[0]);
}

// K4: A[n,hw] = sqrt(S_att)*(sqrt(Mfg)+sqrt(Mbg)) / HW
__global__ __launch_bounds__(256) void k_A(const float* __restrict__ fea_sum,
                                           const float* __restrict__ Mfg,
                                           const float* __restrict__ bgcnt,
                                           const float* __restrict__ stats,
                                           float* __restrict__ A) {
    const int n = blockIdx.y;
    const int hw = blockIdx.x * 256 + threadIdx.x;
    const float smax = stats[n], sden = stats[N_ + n];
    const float logit = fea_sum[n * HW_ + hw] * (1.0f / (C_ * TEMP));
    const float S_att = (float)HW_ * expf(logit - smax) / sden;
    const float fg = Mfg[n * HW_ + hw];
    const float s = bgcnt[n];
    const float bg = (fg <= 0.f) ? ((s > 0.f) ? 1.0f / s : 1.0f) : 0.f;
    A[n * HW_ + hw] = sqrtf(S_att) * (sqrtf(fg) + sqrtf(bg)) * (1.0f / (float)HW_);
}

// K5: main weighted-L1 reduction. grid: 1024 blocks x 256 threads = 4096 waves.
// wave -> fixed n (wg&7), 32 consecutive rows; lane owns c = lane*4..+3 with
// B in registers; A is a per-row broadcast load. Block partial -> ws.
__global__ __launch_bounds__(256) void k_main(const float* __restrict__ pS,
                                              const float* __restrict__ pT,
                                              const float* __restrict__ A,
                                              const float* __restrict__ B,
                                              float* __restrict__ partials) {
    const int wave = threadIdx.x >> 6, lane = threadIdx.x & 63;
    const int wg = blockIdx.x * 4 + wave;      // 0..4095
    const int n = wg & 7;
    const int widx = wg >> 3;                  // 0..511
    const float4 B4 = *(const float4*)(B + n * C_ + lane * 4);
    float acc = 0.f;
    const int hw0 = widx * 32;
    for (int i = 0; i < 32; ++i) {
        const int hw = hw0 + i;
        const size_t off = ((size_t)(hw * N_ + n)) * C_ + lane * 4;
        const float4 sv = *(const float4*)(pS + off);
        const float4 tv = *(const float4*)(pT + off);
        const float part = fabsf(sv.x - tv.x) * B4.x + fabsf(sv.y - tv.y) * B4.y +
                           fabsf(sv.z - tv.z) * B4.z + fabsf(sv.w - tv.w) * B4.w;
        acc += A[n * HW_ + hw] * part;
    }
    acc = waveReduceSum(acc);
    __shared__ float red[4];
    if (lane == 0) red[wave] = acc;
    __syncthreads();
    if (threadIdx.x == 0) partials[blockIdx.x] = red[0] + red[1] + red[2] + red[3];
}

// K6: deterministic finalize: sum 1024 block partials -> d_out[0]
__global__ __launch_bounds__(256) void k_final(const float* __restrict__ partials,
                                               float* __restrict__ out) {
    float a = 0.f;
    for (int i = threadIdx.x; i < 1024; i += 256) a += partials[i];
    __shared__ float red[256];
    red[threadIdx.x] = a; __syncthreads();
    for (int s = 128; s > 0; s >>= 1) { if (threadIdx.x < s) red[threadIdx.x] += red[threadIdx.x + s]; __syncthreads(); }
    if (threadIdx.x == 0) out[0] = red[0];
}

extern "C" void kernel_launch(void* const* d_in, const int* in_sizes, int n_in,
                              void* d_out, int out_size, void* d_ws, size_t ws_size,
                              hipStream_t stream) {
    const float* pS = (const float*)d_in[0];
    const float* pT = (const float*)d_in[1];
    const float* gt = (const float*)d_in[2];
    float* ws = (float*)d_ws;

    // workspace layout (floats)
    float* chan_sum = ws;                    // 2048   (atomics -> zero)
    float* bgcnt    = ws + 2048;             // 8      (atomics -> zero)
    float* stats    = ws + 2056;             // 16     (written)
    float* fea_sum  = ws + 4096;             // 131072 (written)
    float* Mfg      = fea_sum + N_ * HW_;    // 131072 (written)
    float* A        = Mfg + N_ * HW_;        // 131072 (written)
    float* B        = A + N_ * HW_;          // 2048   (written)
    float* partials = B + N_ * C_;           // 1024   (written)

    hipMemsetAsync(ws, 0, 2056 * sizeof(float), stream);

    k_stats<<<512, 256, 0, stream>>>(pT, chan_sum, fea_sum);
    k_soft<<<N_, 256, 0, stream>>>(fea_sum, chan_sum, stats, B);
    k_mask<<<dim3(HW_ / 256, N_), 256, 0, stream>>>(gt, Mfg, bgcnt);
    k_A<<<dim3(HW_ / 256, N_), 256, 0, stream>>>(fea_sum, Mfg, bgcnt, stats, A);
    k_main<<<1024, 256, 0, stream>>>(pS, pT, A, B, partials);
    k_final<<<1, 256, 0, stream>>>(partials, (float*)d_out);
}